// Round 3
// baseline (450.089 us; speedup 1.0000x reference)
//
#include <hip/hip_runtime.h>
#include <hip/hip_bf16.h>
#include <cstring>

#define N_NODES 50000
#define N_EDGES 800000
#define IN_CH 128
#define NG 500
#define OUT_ELEMS 9782000
#define NBUCK 196  // 256-node buckets: ceil(50000/256)
#define DROWS 64

using bf16 = __hip_bfloat16;
typedef unsigned short u16;
typedef long long i64;
typedef unsigned long long u64;

__device__ __forceinline__ float b2f(bf16 v) { return __bfloat162float(v); }
__device__ __forceinline__ float tofl(float v) { return v; }
__device__ __forceinline__ float tofl(bf16 v) { return __bfloat162float(v); }
__device__ __forceinline__ float ldflt(const void* p, int i, int f32) {
  return f32 ? ((const float*)p)[i] : b2f(((const bf16*)p)[i]);
}
__device__ __forceinline__ int ldedge(const void* p, int i, int is64) {
  return is64 ? (int)((const i64*)p)[i] : ((const int*)p)[i];
}
__device__ __forceinline__ float sane(float v) {
  if (!isfinite(v)) return 0.f;
  return fminf(fmaxf(v, -65504.f), 65504.f);
}
__device__ __forceinline__ float lrelu(float x) { return x > 0.f ? x : 0.2f * x; }

__device__ __forceinline__ float wsum(float v) {
#pragma unroll
  for (int o = 32; o > 0; o >>= 1) v += __shfl_xor(v, o, 64);
  return v;
}

// d_out is FLOAT32, 9,782,000 elems:
//   xhat@0 (6,400,000) | ehat@6,400,000 (150,000) | zreg@6,550,000 (3,200,000)
//   emb@9,750,000 (32,000)
// Scratch arena (base = d_ws if ws_size>=17.1MB else d_out; in fallback it sits
// inside the xhat region, which only the FINAL dec kernel writes):
//   deg/ss2@0 (200,000) | bcur/sd2@200,000 (200,000)
//   offs@400,000 (200,016) | part@600,016 (256) | flags@600,272 (64)
//   ss@600,448 (200,000) | sd@800,448 (200,000) | csr@1,000,448 (3,200,000)
//   hbuf(bf16)@4,200,448 (6,400,000) | tmp(u64)/hbuf2@10,600,448 (6,400,000)
//   -> ends 17,000,448 < 25,600,000

__global__ void fillsig_kernel(float* __restrict__ out, int n, float v) {
  int i = blockIdx.x * 256 + threadIdx.x;
  if (i < n) out[i] = v;
}

// ---- prep: zero deg + dtype sniffers (direct writes, no finalize pass) ----
__global__ __launch_bounds__(256) void prep_kernel(const u16* __restrict__ xb,
                                                   const int* __restrict__ ei32,
                                                   int* __restrict__ deg,
                                                   int* __restrict__ fl) {
  int bid = blockIdx.x, tid = threadIdx.x;
  if (bid < 196) {
    int i = bid * 256 + tid;
    if (i < N_NODES) deg[i] = 0;
    return;
  }
  __shared__ int c;
  if (tid == 0) c = 0;
  __syncthreads();
  int cnt = 0;
  if (bid == 196) {
#pragma unroll 4
    for (int k = 0; k < 32; ++k) {
      int i = tid + 256 * k;
      u16 u = xb[2 * i];
      int e = (u >> 7) & 0xFF;
      if (e != 0 && (e < 90 || e > 150)) ++cnt;
    }
  } else {
#pragma unroll 4
    for (int k = 0; k < 32; ++k) {
      int i = tid + 256 * k;
      if (ei32[2 * i + 1] == 0) ++cnt;
    }
  }
  atomicAdd(&c, cnt);
  __syncthreads();
  if (tid == 0) fl[bid == 196 ? 7 : 6] = c;
}

// ---- CSR build ----
__global__ void hist_kernel(const void* __restrict__ ei, const int* __restrict__ fl,
                            int* __restrict__ deg) {
  int is64 = fl[6] > 4000;
  int e = blockIdx.x * 256 + threadIdx.x;
  if (e < N_EDGES) {
    unsigned d = (unsigned)ldedge(ei, N_EDGES + e, is64);
    if (d < N_NODES) atomicAdd(&deg[d], 1);
  }
}

__global__ __launch_bounds__(1024) void scan1_kernel(const int* __restrict__ deg,
                                                     int* __restrict__ offs,
                                                     int* __restrict__ part, int n) {
  __shared__ int sm[1024];
  int t = threadIdx.x;
  int idx = blockIdx.x * 1024 + t;
  int v = (idx < n) ? deg[idx] : 0;
  sm[t] = v;
  __syncthreads();
  for (int off = 1; off < 1024; off <<= 1) {
    int add = (t >= off) ? sm[t - off] : 0;
    __syncthreads();
    sm[t] += add;
    __syncthreads();
  }
  if (idx < n) offs[idx] = sm[t] - v;
  if (t == 1023) part[blockIdx.x] = sm[1023];
}

// finalizes offs (folding the serial partial-prefix), sets offs[n], and
// initializes the 256-node-bucket cursors. part[] holds raw per-1024 sums.
__global__ void scan3_kernel(int* __restrict__ offs, const int* __restrict__ part,
                             int* __restrict__ bcur, int n) {
  __shared__ int pbase;
  int b = blockIdx.x;
  int tid = threadIdx.x;
  if (tid == 0) {
    int bucket = b >> 2;  // (b*256)>>10, constant within block
    int run = 0;
    for (int q = 0; q < bucket; ++q) run += part[q];
    pbase = run;
  }
  __syncthreads();
  int i = b * 256 + tid;
  if (i < n) {
    int v = offs[i] + pbase;
    offs[i] = v;
    if ((i & 255) == 0) bcur[i >> 8] = v;
  }
  if (i == 0) {
    int run = 0;
    for (int q = 0; q < 49; ++q) run += part[q];
    offs[n] = run;
  }
}

// Phase B: bucket-grouped edge records (256-node buckets).
#define BCHUNK 4096
__global__ __launch_bounds__(256) void bucket_kernel(const void* __restrict__ ei,
                                                     const int* __restrict__ fl,
                                                     int* __restrict__ bcur,
                                                     u64* __restrict__ tmp) {
  __shared__ int hist[NBUCK], run[NBUCK], gbase[NBUCK];
  int tid = threadIdx.x;
  if (tid < NBUCK) { hist[tid] = 0; run[tid] = 0; }
  __syncthreads();
  int is64 = fl[6] > 4000;
  int base = blockIdx.x * BCHUNK;
#pragma unroll
  for (int k = 0; k < 16; ++k) {
    int e = base + k * 256 + tid;
    if (e < N_EDGES) {
      unsigned d = (unsigned)ldedge(ei, N_EDGES + e, is64);
      if (d < N_NODES) atomicAdd(&hist[d >> 8], 1);
    }
  }
  __syncthreads();
  if (tid < NBUCK) {
    int h = hist[tid];
    gbase[tid] = h ? atomicAdd(&bcur[tid], h) : 0;
  }
  __syncthreads();
#pragma unroll
  for (int k = 0; k < 16; ++k) {
    int e = base + k * 256 + tid;
    if (e < N_EDGES) {
      unsigned d = (unsigned)ldedge(ei, N_EDGES + e, is64);
      if (d < N_NODES) {
        unsigned s = (unsigned)ldedge(ei, e, is64);
        if (s >= N_NODES) s = 0;  // keep count consistent with deg histogram
        int pos = gbase[d >> 8] + atomicAdd(&run[d >> 8], 1);
        tmp[pos] = ((u64)s << 32) | (u64)d;
      }
    }
  }
}

// Phase C: one block per 256-node bucket; L2 write locality.
__global__ __launch_bounds__(1024) void scatter2_kernel(const u64* __restrict__ tmp,
                                                        const int* __restrict__ offs,
                                                        int* __restrict__ csr) {
  __shared__ int lcur[256];
  int b = blockIdx.x;
  int tid = threadIdx.x;
  if (tid < 256) lcur[tid] = 0;
  __syncthreads();
  int nodelo = b << 8;
  int beg = offs[nodelo];
  int end = offs[min(nodelo + 256, N_NODES)];
  for (int i = beg + tid; i < end; i += 1024) {
    u64 v = tmp[i];
    int d = (int)(v & 0xFFFFFFFFu);
    int s = (int)(v >> 32);
    unsigned li = (unsigned)(d - nodelo);
    if (li < 256) {
      int pos = offs[d] + atomicAdd(&lcur[li], 1);
      if ((unsigned)pos < N_EDGES) csr[pos] = s;
    }
  }
}

// ---- layer-1 GEMM + scores: 64 rows/block, 16 rows/wave, lane = out col ----
// Per k-quad: 4 coalesced W loads + 16 ds_read_b128 + 64 FMA (amortized weights)
template <int FIN, typename FT>
__device__ void gemm64_compute(float (&xl)[DROWS][FIN], const void* Wv, const void* asv,
                               const void* adv, bf16* __restrict__ h, float* __restrict__ ss,
                               float* __restrict__ sd, int rbase) {
  const FT* W = (const FT*)Wv;
  const FT* as_ = (const FT*)asv;
  const FT* ad_ = (const FT*)adv;
  int lane = threadIdx.x & 63, w = threadIdx.x >> 6;
  int r0 = w * 16;
  float a_s = tofl(as_[lane]), a_d = tofl(ad_[lane]);
  float acc[16];
#pragma unroll
  for (int r = 0; r < 16; ++r) acc[r] = 0.f;
  for (int k = 0; k < FIN; k += 4) {
    float w0 = tofl(W[(k + 0) * 64 + lane]);
    float w1 = tofl(W[(k + 1) * 64 + lane]);
    float w2 = tofl(W[(k + 2) * 64 + lane]);
    float w3 = tofl(W[(k + 3) * 64 + lane]);
#pragma unroll
    for (int r = 0; r < 16; ++r) {
      const float4 xv = *(const float4*)&xl[r0 + r][k];
      acc[r] = fmaf(xv.x, w0, acc[r]);
      acc[r] = fmaf(xv.y, w1, acc[r]);
      acc[r] = fmaf(xv.z, w2, acc[r]);
      acc[r] = fmaf(xv.w, w3, acc[r]);
    }
  }
#pragma unroll
  for (int r = 0; r < 16; ++r) {
    int g = rbase + r0 + r;
    if (g < N_NODES) {
      float a = sane(acc[r]);
      h[g * 64 + lane] = __float2bfloat16(a);
      float vs = wsum(a * a_s);
      float vd = wsum(a * a_d);
      if (lane == 0) { ss[g] = sane(vs); sd[g] = sane(vd); }
    }
  }
}

template <int FIN>
__global__ __launch_bounds__(256) void gemm64_kernel(
    const void* __restrict__ xin, const void* __restrict__ W, const void* __restrict__ asrc,
    const void* __restrict__ adst, const int* __restrict__ fl, bf16* __restrict__ h,
    float* __restrict__ ss, float* __restrict__ sd) {
  __shared__ float xl[DROWS][FIN];
  int wf = fl[7] > 2000;
  int tid = threadIdx.x;
  int rbase = blockIdx.x * DROWS;
  for (int i = tid; i < DROWS * FIN; i += 256) {
    int rr = i / FIN, cc = i % FIN;
    int g = rbase + rr;
    xl[rr][cc] = (g < N_NODES) ? ldflt(xin, g * FIN + cc, wf) : 0.f;
  }
  __syncthreads();
  if (wf)
    gemm64_compute<FIN, float>(xl, W, asrc, adst, h, ss, sd, rbase);
  else
    gemm64_compute<FIN, bf16>(xl, W, asrc, adst, h, ss, sd, rbase);
}

// ---- GAT softmax-aggregate for ONE node (lane = channel), pre-bias ----
// Chunk-of-16 gather batches; the 16 h-loads depend only on csr (not on the
// exp(ss[s]) gather), so both latency chains overlap. Lanes >= cnt carry
// wv=0,s=0 so rounding up is numerically free.
__device__ __forceinline__ float agg_node(const bf16* __restrict__ h,
                                          const float* __restrict__ ss,
                                          const float* __restrict__ sd,
                                          const int* __restrict__ offs,
                                          const int* __restrict__ csr, int d, int lane) {
  float sdd = sd[d];
  int beg = offs[d], end = offs[d + 1];
  beg = max(0, min(beg, N_EDGES));
  end = max(beg, min(end, N_EDGES));
  float wself = __expf(fminf(lrelu(ss[d] + sdd), 60.f));
  float acc = b2f(h[d * 64 + lane]) * wself;
  float dpart = (lane == 0) ? wself : 0.f;
  for (int cb = beg; cb < end; cb += 64) {
    int j = cb + lane;
    int s = 0;
    float wv = 0.f;
    if (j < end) {
      s = csr[j];
      s = ((unsigned)s < N_NODES) ? s : 0;
      wv = __expf(fminf(lrelu(ss[s] + sdd), 60.f));
    }
    dpart += wv;
    int cnt = min(64, end - cb);
    for (int t0 = 0; t0 < cnt; t0 += 16) {
      float hv[16];
#pragma unroll
      for (int q = 0; q < 16; ++q) {
        int sq = __shfl(s, t0 + q, 64);
        hv[q] = b2f(h[sq * 64 + lane]);
      }
#pragma unroll
      for (int q = 0; q < 16; ++q) {
        float wq = __shfl(wv, t0 + q, 64);
        acc = fmaf(hv[q], wq, acc);
      }
    }
  }
  float denom = wsum(dpart);
  return acc / (denom + 1e-16f);
}

// ---- 4-row GEMM + scores epilogue (wave 0 of a 4-row block) ----
template <typename FT>
__device__ void gemm4_compute(float (&xl)[4][64], const void* Wv, const void* asv,
                              const void* adv, bf16* __restrict__ h, float* __restrict__ ss,
                              float* __restrict__ sd, int rbase) {
  const FT* W = (const FT*)Wv;
  const FT* as_ = (const FT*)asv;
  const FT* ad_ = (const FT*)adv;
  int lane = threadIdx.x & 63;
  float a_s = tofl(as_[lane]), a_d = tofl(ad_[lane]);
  float acc0 = 0.f, acc1 = 0.f, acc2 = 0.f, acc3 = 0.f;
  for (int k = 0; k < 64; ++k) {
    float wk = tofl(W[k * 64 + lane]);
    acc0 = fmaf(xl[0][k], wk, acc0);
    acc1 = fmaf(xl[1][k], wk, acc1);
    acc2 = fmaf(xl[2][k], wk, acc2);
    acc3 = fmaf(xl[3][k], wk, acc3);
  }
  float acc[4] = {sane(acc0), sane(acc1), sane(acc2), sane(acc3)};
#pragma unroll
  for (int j = 0; j < 4; ++j) {
    int g = rbase + j;
    h[g * 64 + lane] = __float2bfloat16(acc[j]);
    float vs = wsum(acc[j] * a_s);
    float vd = wsum(acc[j] * a_d);
    if (lane == 0) { ss[g] = sane(vs); sd[g] = sane(vd); }
  }
}

// ---- 4-row linear epilogue (wave 0) ----
template <typename FT>
__device__ void lin4_compute(float (&xl)[4][64], const void* Wv, const void* bv,
                             float* __restrict__ zio, int rbase) {
  const FT* W = (const FT*)Wv;
  const FT* b = (const FT*)bv;
  int lane = threadIdx.x & 63;
  float bl = tofl(b[lane]);
  float acc0 = bl, acc1 = bl, acc2 = bl, acc3 = bl;
  for (int k = 0; k < 64; ++k) {
    float wk = tofl(W[k * 64 + lane]);
    acc0 = fmaf(xl[0][k], wk, acc0);
    acc1 = fmaf(xl[1][k], wk, acc1);
    acc2 = fmaf(xl[2][k], wk, acc2);
    acc3 = fmaf(xl[3][k], wk, acc3);
  }
  float acc[4] = {sane(acc0), sane(acc1), sane(acc2), sane(acc3)};
#pragma unroll
  for (int j = 0; j < 4; ++j) zio[(rbase + j) * 64 + lane] = acc[j];
}

// ---- FUSED layer-1 aggregate (+relu) + layer-2 GEMM: 1 node per wave ----
__global__ __launch_bounds__(256) void agg_gemm_kernel(
    const bf16* __restrict__ hL, const float* __restrict__ ssL, const float* __restrict__ sdL,
    const int* __restrict__ offs, const int* __restrict__ csr, const void* __restrict__ bias,
    const int* __restrict__ fl, const void* __restrict__ W2, const void* __restrict__ as2,
    const void* __restrict__ ad2, bf16* __restrict__ hOut, float* __restrict__ ssOut,
    float* __restrict__ sdOut) {
  __shared__ float o1l[4][64];
  int wf = fl[7] > 2000;
  int lane = threadIdx.x & 63, w = threadIdx.x >> 6;
  int rbase = blockIdx.x * 4;
  float bl = ldflt(bias, lane, wf);
  int d = rbase + w;
  float res = agg_node(hL, ssL, sdL, offs, csr, d, lane) + bl;
  o1l[w][lane] = sane(fmaxf(res, 0.f));  // relu
  __syncthreads();
  if (w == 0) {
    if (wf)
      gemm4_compute<float>(o1l, W2, as2, ad2, hOut, ssOut, sdOut, rbase);
    else
      gemm4_compute<bf16>(o1l, W2, as2, ad2, hOut, ssOut, sdOut, rbase);
  }
}

// ---- FUSED layer-2 aggregate + encoder linear: 1 node per wave ----
__global__ __launch_bounds__(256) void agg_lin_kernel(
    const bf16* __restrict__ hL, const float* __restrict__ ssL, const float* __restrict__ sdL,
    const int* __restrict__ offs, const int* __restrict__ csr, const void* __restrict__ bias,
    const int* __restrict__ fl, const void* __restrict__ linW, const void* __restrict__ linb,
    float* __restrict__ zreg) {
  __shared__ float o2l[4][64];
  int wf = fl[7] > 2000;
  int lane = threadIdx.x & 63, w = threadIdx.x >> 6;
  int rbase = blockIdx.x * 4;
  float bl = ldflt(bias, lane, wf);
  int d = rbase + w;
  float res = agg_node(hL, ssL, sdL, offs, csr, d, lane) + bl;
  o2l[w][lane] = sane(res);  // no relu
  __syncthreads();
  if (w == 0) {
    if (wf)
      lin4_compute<float>(o2l, linW, linb, zreg, rbase);
    else
      lin4_compute<bf16>(o2l, linW, linb, zreg, rbase);
  }
}

// ---- global mean pool: sorted batch -> one block per graph, no atomics ----
__global__ __launch_bounds__(256) void pool_seg_kernel(const float* __restrict__ z,
                                                       const void* __restrict__ batch,
                                                       const int* __restrict__ fl,
                                                       float* __restrict__ emb) {
  __shared__ float sm[4][64];
  __shared__ int bounds[2];
  int g = blockIdx.x;
  int tid = threadIdx.x, lane = tid & 63, w = tid >> 6;
  int is64 = fl[6] > 4000;
  if (tid < 2) {
    int target = g + tid;  // lower_bound(batch, target)
    int lo = 0, hi = N_NODES;
    while (lo < hi) {
      int mid = (lo + hi) >> 1;
      if (ldedge(batch, mid, is64) < target) lo = mid + 1; else hi = mid;
    }
    bounds[tid] = lo;
  }
  __syncthreads();
  int beg = bounds[0], end = bounds[1];
  float acc = 0.f;
  for (int r = beg + w; r < end; r += 4) acc += z[r * 64 + lane];
  sm[w][lane] = acc;
  __syncthreads();
  if (w == 0) {
    float v = sm[0][lane] + sm[1][lane] + sm[2][lane] + sm[3][lane];
    float cnt = (float)max(end - beg, 1);
    emb[g * 64 + lane] = sane(v / cnt);
  }
}

// ---- FUSED decoders: 64 rows/block, 16 rows/wave. t1 rows are wave-private,
// so only the initial load needs a barrier. ----
template <typename FT>
__device__ void dec64_compute(float (&zl)[DROWS][64], float (&t1)[DROWS][64],
                              float (&W2l)[192], const void* xW1v, const void* xb1v,
                              const void* xW2v, const void* xb2v, const void* eW1v,
                              const void* eb1v, const void* eb2v,
                              float* __restrict__ xout, float* __restrict__ eout, int rbase) {
  const FT* xW1 = (const FT*)xW1v;
  const FT* xb1 = (const FT*)xb1v;
  const FT* xW2 = (const FT*)xW2v;
  const FT* xb2 = (const FT*)xb2v;
  const FT* eW1 = (const FT*)eW1v;
  const FT* eb1 = (const FT*)eb1v;
  const FT* eb2 = (const FT*)eb2v;
  int lane = threadIdx.x & 63, w = threadIdx.x >> 6;
  int r0 = w * 16;
  // ---- x decoder phase 1: t1 = relu(z @ xmW1 + b1) ----
  {
    float b1l = tofl(xb1[lane]);
    float acc[16];
#pragma unroll
    for (int r = 0; r < 16; ++r) acc[r] = b1l;
    for (int k = 0; k < 64; k += 4) {
      float w0 = tofl(xW1[(k + 0) * 64 + lane]);
      float w1 = tofl(xW1[(k + 1) * 64 + lane]);
      float w2 = tofl(xW1[(k + 2) * 64 + lane]);
      float w3 = tofl(xW1[(k + 3) * 64 + lane]);
#pragma unroll
      for (int r = 0; r < 16; ++r) {
        const float4 zv = *(const float4*)&zl[r0 + r][k];
        acc[r] = fmaf(zv.x, w0, acc[r]);
        acc[r] = fmaf(zv.y, w1, acc[r]);
        acc[r] = fmaf(zv.z, w2, acc[r]);
        acc[r] = fmaf(zv.w, w3, acc[r]);
      }
    }
#pragma unroll
    for (int r = 0; r < 16; ++r) t1[r0 + r][lane] = fmaxf(acc[r], 0.f);
  }
  // ---- x decoder phase 2: xout = t1 @ xmW2 + b2 (64->128) ----
  {
    float b2a = tofl(xb2[lane]), b2b = tofl(xb2[64 + lane]);
    float a0[16], a1[16];
#pragma unroll
    for (int r = 0; r < 16; ++r) { a0[r] = b2a; a1[r] = b2b; }
    for (int k = 0; k < 64; k += 4) {
      float wa0 = tofl(xW2[(k + 0) * 128 + lane]), wb0 = tofl(xW2[(k + 0) * 128 + 64 + lane]);
      float wa1 = tofl(xW2[(k + 1) * 128 + lane]), wb1 = tofl(xW2[(k + 1) * 128 + 64 + lane]);
      float wa2 = tofl(xW2[(k + 2) * 128 + lane]), wb2 = tofl(xW2[(k + 2) * 128 + 64 + lane]);
      float wa3 = tofl(xW2[(k + 3) * 128 + lane]), wb3 = tofl(xW2[(k + 3) * 128 + 64 + lane]);
#pragma unroll
      for (int r = 0; r < 16; ++r) {
        const float4 tv = *(const float4*)&t1[r0 + r][k];
        a0[r] = fmaf(tv.x, wa0, a0[r]);
        a1[r] = fmaf(tv.x, wb0, a1[r]);
        a0[r] = fmaf(tv.y, wa1, a0[r]);
        a1[r] = fmaf(tv.y, wb1, a1[r]);
        a0[r] = fmaf(tv.z, wa2, a0[r]);
        a1[r] = fmaf(tv.z, wb2, a1[r]);
        a0[r] = fmaf(tv.w, wa3, a0[r]);
        a1[r] = fmaf(tv.w, wb3, a1[r]);
      }
    }
#pragma unroll
    for (int r = 0; r < 16; ++r) {
      int g = rbase + r0 + r;
      if (g < N_NODES) {
        xout[g * 128 + lane] = sane(a0[r]);
        xout[g * 128 + 64 + lane] = sane(a1[r]);
      }
    }
  }
  // ---- e decoder phase 1: t1 = relu(z @ emW1 + b1) (overwrite, wave-private) ----
  {
    float b1l = tofl(eb1[lane]);
    float acc[16];
#pragma unroll
    for (int r = 0; r < 16; ++r) acc[r] = b1l;
    for (int k = 0; k < 64; k += 4) {
      float w0 = tofl(eW1[(k + 0) * 64 + lane]);
      float w1 = tofl(eW1[(k + 1) * 64 + lane]);
      float w2 = tofl(eW1[(k + 2) * 64 + lane]);
      float w3 = tofl(eW1[(k + 3) * 64 + lane]);
#pragma unroll
      for (int r = 0; r < 16; ++r) {
        const float4 zv = *(const float4*)&zl[r0 + r][k];
        acc[r] = fmaf(zv.x, w0, acc[r]);
        acc[r] = fmaf(zv.y, w1, acc[r]);
        acc[r] = fmaf(zv.z, w2, acc[r]);
        acc[r] = fmaf(zv.w, w3, acc[r]);
      }
    }
#pragma unroll
    for (int r = 0; r < 16; ++r) t1[r0 + r][lane] = fmaxf(acc[r], 0.f);
  }
  // ---- e decoder phase 2: eout = t1 @ emW2 + b2 (64->3) ----
  {
    int jj = lane >> 4, c = lane & 15;
    if (c < 3) {
      float accv[4];
#pragma unroll
      for (int m = 0; m < 4; ++m) accv[m] = tofl(eb2[c]);
      for (int k = 0; k < 64; ++k) {
        float wv = W2l[k * 3 + c];
#pragma unroll
        for (int m = 0; m < 4; ++m) accv[m] = fmaf(t1[r0 + jj + 4 * m][k], wv, accv[m]);
      }
#pragma unroll
      for (int m = 0; m < 4; ++m) {
        int g = rbase + r0 + jj + 4 * m;
        if (g < N_NODES) eout[g * 3 + c] = sane(accv[m]);
      }
    }
  }
}

__global__ __launch_bounds__(256) void dec_kernel(
    const float* __restrict__ z, const void* __restrict__ xmW1, const void* __restrict__ xmb1,
    const void* __restrict__ xmW2, const void* __restrict__ xmb2, const void* __restrict__ emW1,
    const void* __restrict__ emb1, const void* __restrict__ emW2, const void* __restrict__ emb2,
    const int* __restrict__ fl, float* __restrict__ xout, float* __restrict__ eout) {
  __shared__ float zl[DROWS][64];
  __shared__ float t1[DROWS][64];
  __shared__ float W2l[192];
  int wf = fl[7] > 2000;
  int tid = threadIdx.x;
  int rbase = blockIdx.x * DROWS;
  for (int i = tid; i < DROWS * 64; i += 256) {
    int rr = i >> 6, cc = i & 63;
    int g = rbase + rr;
    zl[rr][cc] = (g < N_NODES) ? z[g * 64 + cc] : 0.f;
  }
  if (tid < 192) W2l[tid] = wf ? ((const float*)emW2)[tid] : b2f(((const bf16*)emW2)[tid]);
  __syncthreads();
  if (wf)
    dec64_compute<float>(zl, t1, W2l, xmW1, xmb1, xmW2, xmb2, emW1, emb1, emb2, xout, eout, rbase);
  else
    dec64_compute<bf16>(zl, t1, W2l, xmW1, xmb1, xmW2, xmb2, emW1, emb1, emb2, xout, eout, rbase);
}

extern "C" void kernel_launch(void* const* d_in, const int* in_sizes, int n_in,
                              void* d_out, int out_size, void* d_ws, size_t ws_size,
                              hipStream_t stream) {
  float* outf = (float*)d_out;
  if (out_size != OUT_ELEMS) {
    float sig = 2048.0f + fminf((float)out_size * 1e-4f, 999.f);
    fillsig_kernel<<<(out_size + 255) / 256, 256, 0, stream>>>(outf, out_size, sig);
    return;
  }
  if (n_in < 22 || in_sizes[0] != N_NODES * IN_CH || in_sizes[1] != 2 * N_EDGES) {
    fillsig_kernel<<<(out_size + 255) / 256, 256, 0, stream>>>(outf, out_size, 5000.f);
    return;
  }

  const void* x = d_in[0];
  const void* ei = d_in[1];
  const void* batch = d_in[2];
  const void* W1 = d_in[4];
  const void* as1 = d_in[5];
  const void* ad1 = d_in[6];
  const void* b1 = d_in[7];
  const void* W2 = d_in[8];
  const void* as2 = d_in[9];
  const void* ad2 = d_in[10];
  const void* b2 = d_in[11];
  const void* linW = d_in[12];
  const void* linb = d_in[13];
  const void* xmW1 = d_in[14];
  const void* xmb1 = d_in[15];
  const void* xmW2 = d_in[16];
  const void* xmb2 = d_in[17];
  const void* emW1 = d_in[18];
  const void* emb1 = d_in[19];
  const void* emW2 = d_in[20];
  const void* emb2 = d_in[21];

  float* xhat = outf;                 // [50000,128] f32
  float* ehat = outf + 6400000;       // [50000,3]
  float* zreg = outf + 6550000;       // [50000,64]  z (f32)
  float* emb = outf + 9750000;        // [500,64]

  bool usews = ws_size >= (size_t)17100000;
  char* base = usews ? (char*)d_ws : (char*)d_out;  // scratch in xhat region if !usews
  int* deg = (int*)(base + 0);
  int* bcur = (int*)(base + 200000);
  int* offs = (int*)(base + 400000);
  int* part = (int*)(base + 600016);
  int* flags = (int*)(base + 600272);
  float* ssb = (float*)(base + 600448);
  float* sdb = (float*)(base + 800448);
  int* csr = (int*)(base + 1000448);
  bf16* hbuf = (bf16*)(base + 4200448);
  u64* tmp = (u64*)(base + 10600448);  // ends 17,000,448 < 25,600,000
  // dead-region reuse after scatter2:
  float* ss2 = (float*)(base + 0);       // over deg
  float* sd2 = (float*)(base + 200000);  // over bcur
  bf16* hbuf2 = (bf16*)(base + 10600448);  // over tmp

  int err = 0, idx = 0;
  (void)hipGetLastError();
#define CK()                                                                       \
  do {                                                                             \
    ++idx;                                                                         \
    hipError_t e_ = hipGetLastError();                                             \
    if (e_ != hipSuccess && err == 0) err = 8192 + idx * 256 + ((int)e_ & 3) * 64; \
  } while (0)

  // 1: zero deg + dtype sniffs
  prep_kernel<<<198, 256, 0, stream>>>((const u16*)x, (const int*)ei, deg, flags); CK();
  // 2-6: CSR build
  hist_kernel<<<N_EDGES / 256, 256, 0, stream>>>(ei, flags, deg); CK();
  scan1_kernel<<<49, 1024, 0, stream>>>(deg, offs, part, N_NODES); CK();
  scan3_kernel<<<(N_NODES + 255) / 256, 256, 0, stream>>>(offs, part, bcur, N_NODES); CK();
  bucket_kernel<<<(N_EDGES + BCHUNK - 1) / BCHUNK, 256, 0, stream>>>(ei, flags, bcur, tmp); CK();
  scatter2_kernel<<<NBUCK, 1024, 0, stream>>>(tmp, offs, csr); CK();
  // 7: layer-1 GEMM (x @ W1) + attention scores (64 rows/block)
  gemm64_kernel<IN_CH><<<(N_NODES + DROWS - 1) / DROWS, 256, 0, stream>>>(
      x, W1, as1, ad1, flags, hbuf, ssb, sdb); CK();
  // 8: fused layer-1 aggregate(+relu) + layer-2 GEMM (1 node/wave)
  agg_gemm_kernel<<<N_NODES / 4, 256, 0, stream>>>(hbuf, ssb, sdb, offs, csr, b1, flags,
                                                   W2, as2, ad2, hbuf2, ss2, sd2); CK();
  // 9: fused layer-2 aggregate + encoder linear (1 node/wave)
  agg_lin_kernel<<<N_NODES / 4, 256, 0, stream>>>(hbuf2, ss2, sd2, offs, csr, b2, flags,
                                                  linW, linb, zreg); CK();
  // 10: pooled embedding
  pool_seg_kernel<<<NG, 256, 0, stream>>>(zreg, batch, flags, emb); CK();
  // 11: fused decoders LAST (xhat write clobbers d_out-arena scratch if !usews)
  dec_kernel<<<(N_NODES + DROWS - 1) / DROWS, 256, 0, stream>>>(
      zreg, xmW1, xmb1, xmW2, xmb2, emW1, emb1, emW2, emb2, flags, xhat, ehat); CK();
#undef CK

  if (err != 0) {
    static float s_sent;
    s_sent = (float)err;
    (void)hipMemcpyAsync(d_out, &s_sent, 4, hipMemcpyHostToDevice, stream);
  }
}

// Round 4
// 371.491 us; speedup vs baseline: 1.2116x; 1.2116x over previous
//
#include <hip/hip_runtime.h>
#include <hip/hip_bf16.h>
#include <cstring>

#define N_NODES 50000
#define N_EDGES 800000
#define IN_CH 128
#define NG 500
#define OUT_ELEMS 9782000
#define NBUCK 196  // 256-node buckets: ceil(50000/256)
#define DR 32      // rows/block for dense tiles (8 rows/wave -> acc[8], no spills)

using bf16 = __hip_bfloat16;
typedef unsigned short u16;
typedef unsigned int u32;
typedef long long i64;
typedef unsigned long long u64;

__device__ __forceinline__ float b2f(bf16 v) { return __bfloat162float(v); }
__device__ __forceinline__ float tofl(float v) { return v; }
__device__ __forceinline__ float tofl(bf16 v) { return __bfloat162float(v); }
__device__ __forceinline__ float ldflt(const void* p, int i, int f32) {
  return f32 ? ((const float*)p)[i] : b2f(((const bf16*)p)[i]);
}
__device__ __forceinline__ int ldedge(const void* p, int i, int is64) {
  return is64 ? (int)((const i64*)p)[i] : ((const int*)p)[i];
}
__device__ __forceinline__ float sane(float v) {
  if (!isfinite(v)) return 0.f;
  return fminf(fmaxf(v, -65504.f), 65504.f);
}
__device__ __forceinline__ float lrelu(float x) { return x > 0.f ? x : 0.2f * x; }
// exact bf16->f32 unpack of a 2xbf16 word (low elem = low 16 bits)
__device__ __forceinline__ float bflo(u32 u) { return __uint_as_float(u << 16); }
__device__ __forceinline__ float bfhi(u32 u) { return __uint_as_float(u & 0xffff0000u); }

__device__ __forceinline__ float wsum(float v) {
#pragma unroll
  for (int o = 32; o > 0; o >>= 1) v += __shfl_xor(v, o, 64);
  return v;
}

// d_out is FLOAT32, 9,782,000 elems:
//   xhat@0 (6,400,000) | ehat@6,400,000 (150,000) | zreg@6,550,000 (3,200,000)
//   emb@9,750,000 (32,000)
// Scratch arena (base = d_ws if ws_size>=17.1MB else d_out; in fallback it sits
// inside the xhat region, which only the FINAL dec kernel writes):
//   deg/ss2@0 (200,000) | bcur/sd2@200,000 (200,000)
//   offs@400,000 (200,016) | part@600,016 (256) | flags@600,272 (64)
//   ss@600,448 (200,000) | sd@800,448 (200,000) | csr@1,000,448 (3,200,000)
//   hbuf(bf16)@4,200,448 (6,400,000) | tmp(u64)/hbuf2@10,600,448 (6,400,000)
//   -> ends 17,000,448 < 25,600,000

__global__ void fillsig_kernel(float* __restrict__ out, int n, float v) {
  int i = blockIdx.x * 256 + threadIdx.x;
  if (i < n) out[i] = v;
}

// ---- prep: zero deg + dtype sniffers (direct writes, no finalize pass) ----
__global__ __launch_bounds__(256) void prep_kernel(const u16* __restrict__ xb,
                                                   const int* __restrict__ ei32,
                                                   int* __restrict__ deg,
                                                   int* __restrict__ fl) {
  int bid = blockIdx.x, tid = threadIdx.x;
  if (bid < 196) {
    int i = bid * 256 + tid;
    if (i < N_NODES) deg[i] = 0;
    return;
  }
  __shared__ int c;
  if (tid == 0) c = 0;
  __syncthreads();
  int cnt = 0;
  if (bid == 196) {
#pragma unroll 4
    for (int k = 0; k < 32; ++k) {
      int i = tid + 256 * k;
      u16 u = xb[2 * i];
      int e = (u >> 7) & 0xFF;
      if (e != 0 && (e < 90 || e > 150)) ++cnt;
    }
  } else {
#pragma unroll 4
    for (int k = 0; k < 32; ++k) {
      int i = tid + 256 * k;
      if (ei32[2 * i + 1] == 0) ++cnt;
    }
  }
  atomicAdd(&c, cnt);
  __syncthreads();
  if (tid == 0) fl[bid == 196 ? 7 : 6] = c;
}

// ---- CSR build ----
__global__ void hist_kernel(const void* __restrict__ ei, const int* __restrict__ fl,
                            int* __restrict__ deg) {
  int is64 = fl[6] > 4000;
  int e = blockIdx.x * 256 + threadIdx.x;
  if (e < N_EDGES) {
    unsigned d = (unsigned)ldedge(ei, N_EDGES + e, is64);
    if (d < N_NODES) atomicAdd(&deg[d], 1);
  }
}

__global__ __launch_bounds__(1024) void scan1_kernel(const int* __restrict__ deg,
                                                     int* __restrict__ offs,
                                                     int* __restrict__ part, int n) {
  __shared__ int sm[1024];
  int t = threadIdx.x;
  int idx = blockIdx.x * 1024 + t;
  int v = (idx < n) ? deg[idx] : 0;
  sm[t] = v;
  __syncthreads();
  for (int off = 1; off < 1024; off <<= 1) {
    int add = (t >= off) ? sm[t - off] : 0;
    __syncthreads();
    sm[t] += add;
    __syncthreads();
  }
  if (idx < n) offs[idx] = sm[t] - v;
  if (t == 1023) part[blockIdx.x] = sm[1023];
}

// finalizes offs (folding the serial partial-prefix), sets offs[n], and
// initializes the 256-node-bucket cursors. part[] holds raw per-1024 sums.
__global__ void scan3_kernel(int* __restrict__ offs, const int* __restrict__ part,
                             int* __restrict__ bcur, int n) {
  __shared__ int pbase;
  int b = blockIdx.x;
  int tid = threadIdx.x;
  if (tid == 0) {
    int bucket = b >> 2;  // (b*256)>>10, constant within block
    int run = 0;
    for (int q = 0; q < bucket; ++q) run += part[q];
    pbase = run;
  }
  __syncthreads();
  int i = b * 256 + tid;
  if (i < n) {
    int v = offs[i] + pbase;
    offs[i] = v;
    if ((i & 255) == 0) bcur[i >> 8] = v;
  }
  if (i == 0) {
    int run = 0;
    for (int q = 0; q < 49; ++q) run += part[q];
    offs[n] = run;
  }
}

// Phase B: bucket-grouped edge records (256-node buckets).
#define BCHUNK 4096
__global__ __launch_bounds__(256) void bucket_kernel(const void* __restrict__ ei,
                                                     const int* __restrict__ fl,
                                                     int* __restrict__ bcur,
                                                     u64* __restrict__ tmp) {
  __shared__ int hist[NBUCK], run[NBUCK], gbase[NBUCK];
  int tid = threadIdx.x;
  if (tid < NBUCK) { hist[tid] = 0; run[tid] = 0; }
  __syncthreads();
  int is64 = fl[6] > 4000;
  int base = blockIdx.x * BCHUNK;
#pragma unroll
  for (int k = 0; k < 16; ++k) {
    int e = base + k * 256 + tid;
    if (e < N_EDGES) {
      unsigned d = (unsigned)ldedge(ei, N_EDGES + e, is64);
      if (d < N_NODES) atomicAdd(&hist[d >> 8], 1);
    }
  }
  __syncthreads();
  if (tid < NBUCK) {
    int h = hist[tid];
    gbase[tid] = h ? atomicAdd(&bcur[tid], h) : 0;
  }
  __syncthreads();
#pragma unroll
  for (int k = 0; k < 16; ++k) {
    int e = base + k * 256 + tid;
    if (e < N_EDGES) {
      unsigned d = (unsigned)ldedge(ei, N_EDGES + e, is64);
      if (d < N_NODES) {
        unsigned s = (unsigned)ldedge(ei, e, is64);
        if (s >= N_NODES) s = 0;  // keep count consistent with deg histogram
        int pos = gbase[d >> 8] + atomicAdd(&run[d >> 8], 1);
        tmp[pos] = ((u64)s << 32) | (u64)d;
      }
    }
  }
}

// Phase C: one block per 256-node bucket; L2 write locality.
__global__ __launch_bounds__(1024) void scatter2_kernel(const u64* __restrict__ tmp,
                                                        const int* __restrict__ offs,
                                                        int* __restrict__ csr) {
  __shared__ int lcur[256];
  int b = blockIdx.x;
  int tid = threadIdx.x;
  if (tid < 256) lcur[tid] = 0;
  __syncthreads();
  int nodelo = b << 8;
  int beg = offs[nodelo];
  int end = offs[min(nodelo + 256, N_NODES)];
  for (int i = beg + tid; i < end; i += 1024) {
    u64 v = tmp[i];
    int d = (int)(v & 0xFFFFFFFFu);
    int s = (int)(v >> 32);
    unsigned li = (unsigned)(d - nodelo);
    if (li < 256) {
      int pos = offs[d] + atomicAdd(&lcur[li], 1);
      if ((unsigned)pos < N_EDGES) csr[pos] = s;
    }
  }
}

// ---- layer-1 GEMM + scores: 32 rows/block, 8 rows/wave, lane = out col ----
template <int FIN, typename FT>
__device__ void gemm32_compute(float (&xl)[DR][FIN], const void* Wv, const void* asv,
                               const void* adv, bf16* __restrict__ h, float* __restrict__ ss,
                               float* __restrict__ sd, int rbase) {
  const FT* W = (const FT*)Wv;
  const FT* as_ = (const FT*)asv;
  const FT* ad_ = (const FT*)adv;
  int lane = threadIdx.x & 63, w = threadIdx.x >> 6;
  int r0 = w * 8;
  float a_s = tofl(as_[lane]), a_d = tofl(ad_[lane]);
  float acc[8];
#pragma unroll
  for (int r = 0; r < 8; ++r) acc[r] = 0.f;
  for (int k = 0; k < FIN; k += 4) {
    float w0 = tofl(W[(k + 0) * 64 + lane]);
    float w1 = tofl(W[(k + 1) * 64 + lane]);
    float w2 = tofl(W[(k + 2) * 64 + lane]);
    float w3 = tofl(W[(k + 3) * 64 + lane]);
#pragma unroll
    for (int r = 0; r < 8; ++r) {
      const float4 xv = *(const float4*)&xl[r0 + r][k];
      acc[r] = fmaf(xv.x, w0, acc[r]);
      acc[r] = fmaf(xv.y, w1, acc[r]);
      acc[r] = fmaf(xv.z, w2, acc[r]);
      acc[r] = fmaf(xv.w, w3, acc[r]);
    }
  }
#pragma unroll
  for (int r = 0; r < 8; ++r) {
    int g = rbase + r0 + r;
    if (g < N_NODES) {
      float a = sane(acc[r]);
      h[g * 64 + lane] = __float2bfloat16(a);
      float vs = wsum(a * a_s);
      float vd = wsum(a * a_d);
      if (lane == 0) { ss[g] = sane(vs); sd[g] = sane(vd); }
    }
  }
}

template <int FIN>
__global__ __launch_bounds__(256) void gemm32_kernel(
    const void* __restrict__ xin, const void* __restrict__ W, const void* __restrict__ asrc,
    const void* __restrict__ adst, const int* __restrict__ fl, bf16* __restrict__ h,
    float* __restrict__ ss, float* __restrict__ sd) {
  __shared__ float xl[DR][FIN];
  int wf = fl[7] > 2000;
  int tid = threadIdx.x;
  int rbase = blockIdx.x * DR;
  for (int i = tid; i < DR * FIN; i += 256) {
    int rr = i / FIN, cc = i % FIN;
    int g = rbase + rr;
    xl[rr][cc] = (g < N_NODES) ? ldflt(xin, g * FIN + cc, wf) : 0.f;
  }
  __syncthreads();
  if (wf)
    gemm32_compute<FIN, float>(xl, W, asrc, adst, h, ss, sd, rbase);
  else
    gemm32_compute<FIN, bf16>(xl, W, asrc, adst, h, ss, sd, rbase);
}

// ---- GAT softmax-aggregate, TWO nodes per wave, 2 channels per lane ----
// Lanes 0-31 serve node dA's 64 channels as 2xbf16 words; lanes 32-63 serve
// dB. Per-edge loads/shuffles/fmas are shared by both halves -> per-edge
// wave-instruction cost halves vs 1-node/wave. FMA order per channel is
// unchanged (edge-ascending), bf16 unpack is bit-exact.
__device__ __forceinline__ float2 agg_node2(const bf16* __restrict__ h,
                                            const float* __restrict__ ss,
                                            const float* __restrict__ sd,
                                            const int* __restrict__ offs,
                                            const int* __restrict__ csr, int d, int lane) {
  int hl = lane & 31;
  int hbase = lane & 32;  // own half's lane base for broadcasts
  float sdd = sd[d];
  int beg = offs[d], end = offs[d + 1];
  beg = max(0, min(beg, N_EDGES));
  end = max(beg, min(end, N_EDGES));
  float wself = __expf(fminf(lrelu(ss[d] + sdd), 60.f));
  u32 uself = ((const u32*)h)[d * 32 + hl];
  float2 acc;
  acc.x = bflo(uself) * wself;
  acc.y = bfhi(uself) * wself;
  float dpart = (hl == 0) ? wself : 0.f;
  for (int cb = beg; cb < end; cb += 32) {
    int j = cb + hl;
    int s = 0;
    float wv = 0.f;
    if (j < end) {
      s = csr[j];
      s = ((unsigned)s < N_NODES) ? s : 0;
      wv = __expf(fminf(lrelu(ss[s] + sdd), 60.f));
    }
    dpart += wv;
    int cnt = min(32, end - cb);
    for (int t0 = 0; t0 < cnt; t0 += 16) {
      u32 hv[16];
#pragma unroll
      for (int q = 0; q < 16; ++q) {
        int sq = __shfl(s, hbase + t0 + q, 64);
        hv[q] = ((const u32*)h)[sq * 32 + hl];
      }
#pragma unroll
      for (int q = 0; q < 16; ++q) {
        float wq = __shfl(wv, hbase + t0 + q, 64);
        acc.x = fmaf(bflo(hv[q]), wq, acc.x);
        acc.y = fmaf(bfhi(hv[q]), wq, acc.y);
      }
    }
  }
  // half-wide (32-lane) reduction of the denominator
#pragma unroll
  for (int o = 16; o > 0; o >>= 1) dpart += __shfl_xor(dpart, o, 64);
  float den = dpart + 1e-16f;
  acc.x = acc.x / den;
  acc.y = acc.y / den;
  return acc;
}

// ---- 4-row GEMM + scores epilogue (any single wave) ----
template <typename FT>
__device__ void gemm4_compute(float (&xl)[4][64], const void* Wv, const void* asv,
                              const void* adv, bf16* __restrict__ h, float* __restrict__ ss,
                              float* __restrict__ sd, int rbase) {
  const FT* W = (const FT*)Wv;
  const FT* as_ = (const FT*)asv;
  const FT* ad_ = (const FT*)adv;
  int lane = threadIdx.x & 63;
  float a_s = tofl(as_[lane]), a_d = tofl(ad_[lane]);
  float acc0 = 0.f, acc1 = 0.f, acc2 = 0.f, acc3 = 0.f;
  for (int k = 0; k < 64; ++k) {
    float wk = tofl(W[k * 64 + lane]);
    acc0 = fmaf(xl[0][k], wk, acc0);
    acc1 = fmaf(xl[1][k], wk, acc1);
    acc2 = fmaf(xl[2][k], wk, acc2);
    acc3 = fmaf(xl[3][k], wk, acc3);
  }
  float acc[4] = {sane(acc0), sane(acc1), sane(acc2), sane(acc3)};
#pragma unroll
  for (int j = 0; j < 4; ++j) {
    int g = rbase + j;
    h[g * 64 + lane] = __float2bfloat16(acc[j]);
    float vs = wsum(acc[j] * a_s);
    float vd = wsum(acc[j] * a_d);
    if (lane == 0) { ss[g] = sane(vs); sd[g] = sane(vd); }
  }
}

// ---- 4-row linear epilogue (any single wave) ----
template <typename FT>
__device__ void lin4_compute(float (&xl)[4][64], const void* Wv, const void* bv,
                             float* __restrict__ zio, int rbase) {
  const FT* W = (const FT*)Wv;
  const FT* b = (const FT*)bv;
  int lane = threadIdx.x & 63;
  float bl = tofl(b[lane]);
  float acc0 = bl, acc1 = bl, acc2 = bl, acc3 = bl;
  for (int k = 0; k < 64; ++k) {
    float wk = tofl(W[k * 64 + lane]);
    acc0 = fmaf(xl[0][k], wk, acc0);
    acc1 = fmaf(xl[1][k], wk, acc1);
    acc2 = fmaf(xl[2][k], wk, acc2);
    acc3 = fmaf(xl[3][k], wk, acc3);
  }
  float acc[4] = {sane(acc0), sane(acc1), sane(acc2), sane(acc3)};
#pragma unroll
  for (int j = 0; j < 4; ++j) zio[(rbase + j) * 64 + lane] = acc[j];
}

// ---- FUSED layer-1 aggregate (+relu) + layer-2 GEMM: 8 nodes/block ----
__global__ __launch_bounds__(256) void agg_gemm_kernel(
    const bf16* __restrict__ hL, const float* __restrict__ ssL, const float* __restrict__ sdL,
    const int* __restrict__ offs, const int* __restrict__ csr, const void* __restrict__ bias,
    const int* __restrict__ fl, const void* __restrict__ W2, const void* __restrict__ as2,
    const void* __restrict__ ad2, bf16* __restrict__ hOut, float* __restrict__ ssOut,
    float* __restrict__ sdOut) {
  __shared__ float o1l[8][64];
  int wf = fl[7] > 2000;
  int lane = threadIdx.x & 63, w = threadIdx.x >> 6;
  int hl = lane & 31, half = lane >> 5;
  int rbase = blockIdx.x * 8;
  int d = rbase + 2 * w + half;
  float2 r = agg_node2(hL, ssL, sdL, offs, csr, d, lane);
  float blx = ldflt(bias, 2 * hl, wf), bly = ldflt(bias, 2 * hl + 1, wf);
  o1l[2 * w + half][2 * hl] = sane(fmaxf(r.x + blx, 0.f));      // relu
  o1l[2 * w + half][2 * hl + 1] = sane(fmaxf(r.y + bly, 0.f));  // relu
  __syncthreads();
  if (w < 2) {
    float(&sub)[4][64] = *reinterpret_cast<float(*)[4][64]>(&o1l[4 * w]);
    if (wf)
      gemm4_compute<float>(sub, W2, as2, ad2, hOut, ssOut, sdOut, rbase + 4 * w);
    else
      gemm4_compute<bf16>(sub, W2, as2, ad2, hOut, ssOut, sdOut, rbase + 4 * w);
  }
}

// ---- FUSED layer-2 aggregate + encoder linear: 8 nodes/block ----
__global__ __launch_bounds__(256) void agg_lin_kernel(
    const bf16* __restrict__ hL, const float* __restrict__ ssL, const float* __restrict__ sdL,
    const int* __restrict__ offs, const int* __restrict__ csr, const void* __restrict__ bias,
    const int* __restrict__ fl, const void* __restrict__ linW, const void* __restrict__ linb,
    float* __restrict__ zreg) {
  __shared__ float o2l[8][64];
  int wf = fl[7] > 2000;
  int lane = threadIdx.x & 63, w = threadIdx.x >> 6;
  int hl = lane & 31, half = lane >> 5;
  int rbase = blockIdx.x * 8;
  int d = rbase + 2 * w + half;
  float2 r = agg_node2(hL, ssL, sdL, offs, csr, d, lane);
  float blx = ldflt(bias, 2 * hl, wf), bly = ldflt(bias, 2 * hl + 1, wf);
  o2l[2 * w + half][2 * hl] = sane(r.x + blx);      // no relu
  o2l[2 * w + half][2 * hl + 1] = sane(r.y + bly);  // no relu
  __syncthreads();
  if (w < 2) {
    float(&sub)[4][64] = *reinterpret_cast<float(*)[4][64]>(&o2l[4 * w]);
    if (wf)
      lin4_compute<float>(sub, linW, linb, zreg, rbase + 4 * w);
    else
      lin4_compute<bf16>(sub, linW, linb, zreg, rbase + 4 * w);
  }
}

// ---- global mean pool: sorted batch -> one block per graph, no atomics ----
__global__ __launch_bounds__(256) void pool_seg_kernel(const float* __restrict__ z,
                                                       const void* __restrict__ batch,
                                                       const int* __restrict__ fl,
                                                       float* __restrict__ emb) {
  __shared__ float sm[4][64];
  __shared__ int bounds[2];
  int g = blockIdx.x;
  int tid = threadIdx.x, lane = tid & 63, w = tid >> 6;
  int is64 = fl[6] > 4000;
  if (tid < 2) {
    int target = g + tid;  // lower_bound(batch, target)
    int lo = 0, hi = N_NODES;
    while (lo < hi) {
      int mid = (lo + hi) >> 1;
      if (ldedge(batch, mid, is64) < target) lo = mid + 1; else hi = mid;
    }
    bounds[tid] = lo;
  }
  __syncthreads();
  int beg = bounds[0], end = bounds[1];
  float acc = 0.f;
  for (int r = beg + w; r < end; r += 4) acc += z[r * 64 + lane];
  sm[w][lane] = acc;
  __syncthreads();
  if (w == 0) {
    float v = sm[0][lane] + sm[1][lane] + sm[2][lane] + sm[3][lane];
    float cnt = (float)max(end - beg, 1);
    emb[g * 64 + lane] = sane(v / cnt);
  }
}

// ---- FUSED decoders: 32 rows/block, 8 rows/wave (acc[8] keeps VGPR sane).
// t1 rows are wave-private, so only the initial zl load needs a barrier. ----
template <typename FT>
__device__ void dec32_compute(float (&zl)[DR][64], float (&t1)[DR][64],
                              float (&W2l)[192], const void* xW1v, const void* xb1v,
                              const void* xW2v, const void* xb2v, const void* eW1v,
                              const void* eb1v, const void* eb2v,
                              float* __restrict__ xout, float* __restrict__ eout, int rbase) {
  const FT* xW1 = (const FT*)xW1v;
  const FT* xb1 = (const FT*)xb1v;
  const FT* xW2 = (const FT*)xW2v;
  const FT* xb2 = (const FT*)xb2v;
  const FT* eW1 = (const FT*)eW1v;
  const FT* eb1 = (const FT*)eb1v;
  const FT* eb2 = (const FT*)eb2v;
  int lane = threadIdx.x & 63, w = threadIdx.x >> 6;
  int r0 = w * 8;
  // ---- x decoder phase 1: t1 = relu(z @ xmW1 + b1) ----
  {
    float b1l = tofl(xb1[lane]);
    float acc[8];
#pragma unroll
    for (int r = 0; r < 8; ++r) acc[r] = b1l;
    for (int k = 0; k < 64; k += 4) {
      float w0 = tofl(xW1[(k + 0) * 64 + lane]);
      float w1 = tofl(xW1[(k + 1) * 64 + lane]);
      float w2 = tofl(xW1[(k + 2) * 64 + lane]);
      float w3 = tofl(xW1[(k + 3) * 64 + lane]);
#pragma unroll
      for (int r = 0; r < 8; ++r) {
        const float4 zv = *(const float4*)&zl[r0 + r][k];
        acc[r] = fmaf(zv.x, w0, acc[r]);
        acc[r] = fmaf(zv.y, w1, acc[r]);
        acc[r] = fmaf(zv.z, w2, acc[r]);
        acc[r] = fmaf(zv.w, w3, acc[r]);
      }
    }
#pragma unroll
    for (int r = 0; r < 8; ++r) t1[r0 + r][lane] = fmaxf(acc[r], 0.f);
  }
  // ---- x decoder phase 2: xout = t1 @ xmW2 + b2 (64->128) ----
  {
    float b2a = tofl(xb2[lane]), b2b = tofl(xb2[64 + lane]);
    float a0[8], a1[8];
#pragma unroll
    for (int r = 0; r < 8; ++r) { a0[r] = b2a; a1[r] = b2b; }
    for (int k = 0; k < 64; k += 4) {
      float wa0 = tofl(xW2[(k + 0) * 128 + lane]), wb0 = tofl(xW2[(k + 0) * 128 + 64 + lane]);
      float wa1 = tofl(xW2[(k + 1) * 128 + lane]), wb1 = tofl(xW2[(k + 1) * 128 + 64 + lane]);
      float wa2 = tofl(xW2[(k + 2) * 128 + lane]), wb2 = tofl(xW2[(k + 2) * 128 + 64 + lane]);
      float wa3 = tofl(xW2[(k + 3) * 128 + lane]), wb3 = tofl(xW2[(k + 3) * 128 + 64 + lane]);
#pragma unroll
      for (int r = 0; r < 8; ++r) {
        const float4 tv = *(const float4*)&t1[r0 + r][k];
        a0[r] = fmaf(tv.x, wa0, a0[r]);
        a1[r] = fmaf(tv.x, wb0, a1[r]);
        a0[r] = fmaf(tv.y, wa1, a0[r]);
        a1[r] = fmaf(tv.y, wb1, a1[r]);
        a0[r] = fmaf(tv.z, wa2, a0[r]);
        a1[r] = fmaf(tv.z, wb2, a1[r]);
        a0[r] = fmaf(tv.w, wa3, a0[r]);
        a1[r] = fmaf(tv.w, wb3, a1[r]);
      }
    }
#pragma unroll
    for (int r = 0; r < 8; ++r) {
      int g = rbase + r0 + r;
      if (g < N_NODES) {
        xout[g * 128 + lane] = sane(a0[r]);
        xout[g * 128 + 64 + lane] = sane(a1[r]);
      }
    }
  }
  // ---- e decoder phase 1: t1 = relu(z @ emW1 + b1) (overwrite, wave-private) ----
  {
    float b1l = tofl(eb1[lane]);
    float acc[8];
#pragma unroll
    for (int r = 0; r < 8; ++r) acc[r] = b1l;
    for (int k = 0; k < 64; k += 4) {
      float w0 = tofl(eW1[(k + 0) * 64 + lane]);
      float w1 = tofl(eW1[(k + 1) * 64 + lane]);
      float w2 = tofl(eW1[(k + 2) * 64 + lane]);
      float w3 = tofl(eW1[(k + 3) * 64 + lane]);
#pragma unroll
      for (int r = 0; r < 8; ++r) {
        const float4 zv = *(const float4*)&zl[r0 + r][k];
        acc[r] = fmaf(zv.x, w0, acc[r]);
        acc[r] = fmaf(zv.y, w1, acc[r]);
        acc[r] = fmaf(zv.z, w2, acc[r]);
        acc[r] = fmaf(zv.w, w3, acc[r]);
      }
    }
#pragma unroll
    for (int r = 0; r < 8; ++r) t1[r0 + r][lane] = fmaxf(acc[r], 0.f);
  }
  // ---- e decoder phase 2: eout = t1 @ emW2 + b2 (64->3) ----
  {
    int jj = lane >> 4, c = lane & 15;
    if (c < 3) {
      float accv[2];
#pragma unroll
      for (int m = 0; m < 2; ++m) accv[m] = tofl(eb2[c]);
      for (int k = 0; k < 64; ++k) {
        float wv = W2l[k * 3 + c];
#pragma unroll
        for (int m = 0; m < 2; ++m) accv[m] = fmaf(t1[r0 + jj + 4 * m][k], wv, accv[m]);
      }
#pragma unroll
      for (int m = 0; m < 2; ++m) {
        int g = rbase + r0 + jj + 4 * m;
        if (g < N_NODES) eout[g * 3 + c] = sane(accv[m]);
      }
    }
  }
}

__global__ __launch_bounds__(256) void dec_kernel(
    const float* __restrict__ z, const void* __restrict__ xmW1, const void* __restrict__ xmb1,
    const void* __restrict__ xmW2, const void* __restrict__ xmb2, const void* __restrict__ emW1,
    const void* __restrict__ emb1, const void* __restrict__ emW2, const void* __restrict__ emb2,
    const int* __restrict__ fl, float* __restrict__ xout, float* __restrict__ eout) {
  __shared__ float zl[DR][64];
  __shared__ float t1[DR][64];
  __shared__ float W2l[192];
  int wf = fl[7] > 2000;
  int tid = threadIdx.x;
  int rbase = blockIdx.x * DR;
  for (int i = tid; i < DR * 64; i += 256) {
    int rr = i >> 6, cc = i & 63;
    int g = rbase + rr;
    zl[rr][cc] = (g < N_NODES) ? z[g * 64 + cc] : 0.f;
  }
  if (tid < 192) W2l[tid] = wf ? ((const float*)emW2)[tid] : b2f(((const bf16*)emW2)[tid]);
  __syncthreads();
  if (wf)
    dec32_compute<float>(zl, t1, W2l, xmW1, xmb1, xmW2, xmb2, emW1, emb1, emb2, xout, eout, rbase);
  else
    dec32_compute<bf16>(zl, t1, W2l, xmW1, xmb1, xmW2, xmb2, emW1, emb1, emb2, xout, eout, rbase);
}

extern "C" void kernel_launch(void* const* d_in, const int* in_sizes, int n_in,
                              void* d_out, int out_size, void* d_ws, size_t ws_size,
                              hipStream_t stream) {
  float* outf = (float*)d_out;
  if (out_size != OUT_ELEMS) {
    float sig = 2048.0f + fminf((float)out_size * 1e-4f, 999.f);
    fillsig_kernel<<<(out_size + 255) / 256, 256, 0, stream>>>(outf, out_size, sig);
    return;
  }
  if (n_in < 22 || in_sizes[0] != N_NODES * IN_CH || in_sizes[1] != 2 * N_EDGES) {
    fillsig_kernel<<<(out_size + 255) / 256, 256, 0, stream>>>(outf, out_size, 5000.f);
    return;
  }

  const void* x = d_in[0];
  const void* ei = d_in[1];
  const void* batch = d_in[2];
  const void* W1 = d_in[4];
  const void* as1 = d_in[5];
  const void* ad1 = d_in[6];
  const void* b1 = d_in[7];
  const void* W2 = d_in[8];
  const void* as2 = d_in[9];
  const void* ad2 = d_in[10];
  const void* b2 = d_in[11];
  const void* linW = d_in[12];
  const void* linb = d_in[13];
  const void* xmW1 = d_in[14];
  const void* xmb1 = d_in[15];
  const void* xmW2 = d_in[16];
  const void* xmb2 = d_in[17];
  const void* emW1 = d_in[18];
  const void* emb1 = d_in[19];
  const void* emW2 = d_in[20];
  const void* emb2 = d_in[21];

  float* xhat = outf;                 // [50000,128] f32
  float* ehat = outf + 6400000;       // [50000,3]
  float* zreg = outf + 6550000;       // [50000,64]  z (f32)
  float* emb = outf + 9750000;        // [500,64]

  bool usews = ws_size >= (size_t)17100000;
  char* base = usews ? (char*)d_ws : (char*)d_out;  // scratch in xhat region if !usews
  int* deg = (int*)(base + 0);
  int* bcur = (int*)(base + 200000);
  int* offs = (int*)(base + 400000);
  int* part = (int*)(base + 600016);
  int* flags = (int*)(base + 600272);
  float* ssb = (float*)(base + 600448);
  float* sdb = (float*)(base + 800448);
  int* csr = (int*)(base + 1000448);
  bf16* hbuf = (bf16*)(base + 4200448);
  u64* tmp = (u64*)(base + 10600448);  // ends 17,000,448 < 25,600,000
  // dead-region reuse after scatter2:
  float* ss2 = (float*)(base + 0);       // over deg
  float* sd2 = (float*)(base + 200000);  // over bcur
  bf16* hbuf2 = (bf16*)(base + 10600448);  // over tmp

  int err = 0, idx = 0;
  (void)hipGetLastError();
#define CK()                                                                       \
  do {                                                                             \
    ++idx;                                                                         \
    hipError_t e_ = hipGetLastError();                                             \
    if (e_ != hipSuccess && err == 0) err = 8192 + idx * 256 + ((int)e_ & 3) * 64; \
  } while (0)

  // 1: zero deg + dtype sniffs
  prep_kernel<<<198, 256, 0, stream>>>((const u16*)x, (const int*)ei, deg, flags); CK();
  // 2-6: CSR build
  hist_kernel<<<N_EDGES / 256, 256, 0, stream>>>(ei, flags, deg); CK();
  scan1_kernel<<<49, 1024, 0, stream>>>(deg, offs, part, N_NODES); CK();
  scan3_kernel<<<(N_NODES + 255) / 256, 256, 0, stream>>>(offs, part, bcur, N_NODES); CK();
  bucket_kernel<<<(N_EDGES + BCHUNK - 1) / BCHUNK, 256, 0, stream>>>(ei, flags, bcur, tmp); CK();
  scatter2_kernel<<<NBUCK, 1024, 0, stream>>>(tmp, offs, csr); CK();
  // 7: layer-1 GEMM (x @ W1) + attention scores (32 rows/block, 8/wave)
  gemm32_kernel<IN_CH><<<(N_NODES + DR - 1) / DR, 256, 0, stream>>>(
      x, W1, as1, ad1, flags, hbuf, ssb, sdb); CK();
  // 8: fused layer-1 aggregate(+relu) + layer-2 GEMM (2 nodes/wave, 2 ch/lane)
  agg_gemm_kernel<<<N_NODES / 8, 256, 0, stream>>>(hbuf, ssb, sdb, offs, csr, b1, flags,
                                                   W2, as2, ad2, hbuf2, ss2, sd2); CK();
  // 9: fused layer-2 aggregate + encoder linear (2 nodes/wave, 2 ch/lane)
  agg_lin_kernel<<<N_NODES / 8, 256, 0, stream>>>(hbuf2, ss2, sd2, offs, csr, b2, flags,
                                                  linW, linb, zreg); CK();
  // 10: pooled embedding
  pool_seg_kernel<<<NG, 256, 0, stream>>>(zreg, batch, flags, emb); CK();
  // 11: fused decoders LAST (xhat write clobbers d_out-arena scratch if !usews)
  dec_kernel<<<(N_NODES + DR - 1) / DR, 256, 0, stream>>>(
      zreg, xmW1, xmb1, xmW2, xmb2, emW1, emb1, emW2, emb2, flags, xhat, ehat); CK();
#undef CK

  if (err != 0) {
    static float s_sent;
    s_sent = (float)err;
    (void)hipMemcpyAsync(d_out, &s_sent, 4, hipMemcpyHostToDevice, stream);
  }
}